// Round 1
// baseline (3735.622 us; speedup 1.0000x reference)
//
#include <hip/hip_runtime.h>
#include <math.h>

// G2GDecoder forward: TreeGRU over line graph + topology/label heads.
// All f32. d=128 fixed. M of every GEMM is a multiple of 32.

__device__ inline float wave_sum64(float v){
  #pragma unroll
  for (int m = 32; m; m >>= 1) v += __shfl_xor(v, m, 64);
  return v;
}
__device__ inline float wave_max64(float v){
  #pragma unroll
  for (int m = 32; m; m >>= 1) v = fmaxf(v, __shfl_xor(v, m, 64));
  return v;
}
__device__ inline float sigmoidf_(float x){ return 1.f / (1.f + __expf(-x)); }
__device__ inline float tanh_fast(float x){
  x = fminf(fmaxf(x, -15.f), 15.f);
  float e = __expf(2.f * x);
  return (e - 1.f) / (e + 1.f);
}
__device__ inline float logsigf_(float x){
  // stable log(sigmoid(x))
  return (x >= 0.f) ? -log1pf(__expf(-x)) : (x - log1pf(__expf(x)));
}

enum { EPI_NONE = 0, EPI_SIGMOID = 1, EPI_RELU = 2, EPI_SIGMUL = 3, EPI_GRUMIX = 4 };

// C[M,128] = epi( A1[M,K1] @ W1[K1,128] (+ A2[M,K2] @ W2[K2,128]) + bias )
// EPI_SIGMUL: out = sigmoid(acc+bias) * aux1[row,col]
// EPI_GRUMIX: out = (1-z)*s + z*tanh(acc+bias), z=aux1, s=aux2  (safe in-place over aux2)
__global__ __launch_bounds__(256) void gemm128_kernel(
    int M,
    const float* __restrict__ A1, int K1, const float* __restrict__ W1,
    const float* __restrict__ A2, int K2, const float* __restrict__ W2,
    const float* __restrict__ bias, int epi,
    const float* __restrict__ aux1, const float* __restrict__ aux2,
    float* __restrict__ out)
{
  __shared__ __align__(16) float Wt[32 * 128];  // W k-tile [32][128]
  __shared__ float At[32][33];                  // A tile transposed [kk][row], +1 pad
  const int t = threadIdx.x;
  const int row0 = blockIdx.x * 32;
  const int cg = t & 31;        // col group: cols cg*4 .. cg*4+3
  const int rg = t >> 5;        // row group: rows rg*4 .. rg*4+3
  float acc[4][4] = {};

  for (int src = 0; src < 2; ++src){
    const float* A = src ? A2 : A1;
    const float* W = src ? W2 : W1;
    const int K = src ? K2 : K1;
    if (A == nullptr) break;
    for (int kt = 0; kt < K; kt += 32){
      __syncthreads();
      // load W tile (32x128 floats = 1024 float4, layout-identical flat copy)
      const float4* Wg = (const float4*)(W + (size_t)kt * 128);
      #pragma unroll
      for (int rr = 0; rr < 4; ++rr)
        ((float4*)Wt)[t + rr * 256] = Wg[t + rr * 256];
      // load A tile transposed: rows row0..row0+31, k = kt..kt+31
      {
        const int r = t >> 3, f4 = t & 7;
        float4 a = *(const float4*)(A + (size_t)(row0 + r) * K + kt + f4 * 4);
        At[f4 * 4 + 0][r] = a.x;
        At[f4 * 4 + 1][r] = a.y;
        At[f4 * 4 + 2][r] = a.z;
        At[f4 * 4 + 3][r] = a.w;
      }
      __syncthreads();
      #pragma unroll
      for (int kk = 0; kk < 32; ++kk){
        const float4 w4 = *(const float4*)&Wt[kk * 128 + cg * 4];
        const float a0 = At[kk][rg * 4 + 0];
        const float a1 = At[kk][rg * 4 + 1];
        const float a2 = At[kk][rg * 4 + 2];
        const float a3 = At[kk][rg * 4 + 3];
        acc[0][0] += a0 * w4.x; acc[0][1] += a0 * w4.y; acc[0][2] += a0 * w4.z; acc[0][3] += a0 * w4.w;
        acc[1][0] += a1 * w4.x; acc[1][1] += a1 * w4.y; acc[1][2] += a1 * w4.z; acc[1][3] += a1 * w4.w;
        acc[2][0] += a2 * w4.x; acc[2][1] += a2 * w4.y; acc[2][2] += a2 * w4.z; acc[2][3] += a2 * w4.w;
        acc[3][0] += a3 * w4.x; acc[3][1] += a3 * w4.y; acc[3][2] += a3 * w4.z; acc[3][3] += a3 * w4.w;
      }
    }
  }

  const int colb = cg * 4;
  float bv[4] = {0.f, 0.f, 0.f, 0.f};
  if (bias){
    #pragma unroll
    for (int j = 0; j < 4; ++j) bv[j] = bias[colb + j];
  }
  #pragma unroll
  for (int i = 0; i < 4; ++i){
    const int row = row0 + rg * 4 + i;
    const size_t o = (size_t)row * 128 + colb;
    float v[4];
    #pragma unroll
    for (int j = 0; j < 4; ++j) v[j] = acc[i][j] + bv[j];
    if (epi == EPI_SIGMOID){
      #pragma unroll
      for (int j = 0; j < 4; ++j) v[j] = sigmoidf_(v[j]);
    } else if (epi == EPI_RELU){
      #pragma unroll
      for (int j = 0; j < 4; ++j) v[j] = fmaxf(v[j], 0.f);
    } else if (epi == EPI_SIGMUL){
      const float4 m4 = *(const float4*)(aux1 + o);
      const float mm[4] = {m4.x, m4.y, m4.z, m4.w};
      #pragma unroll
      for (int j = 0; j < 4; ++j) v[j] = sigmoidf_(v[j]) * mm[j];
    } else if (epi == EPI_GRUMIX){
      const float4 z4 = *(const float4*)(aux1 + o);
      const float4 s4 = *(const float4*)(aux2 + o);
      const float zz[4] = {z4.x, z4.y, z4.z, z4.w};
      const float ss[4] = {s4.x, s4.y, s4.z, s4.w};
      #pragma unroll
      for (int j = 0; j < 4; ++j) v[j] = (1.f - zz[j]) * ss[j] + zz[j] * tanh_fast(v[j]);
    }
    *(float4*)(out + o) = make_float4(v[0], v[1], v[2], v[3]);
  }
}

// s[dst] += msg[src]; srh[dst] += R[src]   (per line-graph edge, 32 threads/edge)
__global__ __launch_bounds__(256) void scatter2_kernel(
    const int* __restrict__ lg_src, const int* __restrict__ lg_dst, int ELG,
    const float* __restrict__ msg, const float* __restrict__ R,
    float* __restrict__ s, float* __restrict__ srh)
{
  const int g = blockIdx.x * 256 + threadIdx.x;
  const int e = g >> 5, q = g & 31;
  if (e >= ELG) return;
  const int si = lg_src[e], di = lg_dst[e];
  const float4 m = ((const float4*)msg)[(size_t)si * 32 + q];
  const float4 r = ((const float4*)R)[(size_t)si * 32 + q];
  float* sd = s + (size_t)di * 128 + q * 4;
  float* rd = srh + (size_t)di * 128 + q * 4;
  atomicAdd(sd + 0, m.x); atomicAdd(sd + 1, m.y); atomicAdd(sd + 2, m.z); atomicAdd(sd + 3, m.w);
  atomicAdd(rd + 0, r.x); atomicAdd(rd + 1, r.y); atomicAdd(rd + 2, r.z); atomicAdd(rd + 3, r.w);
}

// dst[lg_dst] += src[lg_src]
__global__ __launch_bounds__(256) void scatter1_kernel(
    const int* __restrict__ lg_src, const int* __restrict__ lg_dst, int ELG,
    const float* __restrict__ src, float* __restrict__ dst)
{
  const int g = blockIdx.x * 256 + threadIdx.x;
  const int e = g >> 5, q = g & 31;
  if (e >= ELG) return;
  const int si = lg_src[e], di = lg_dst[e];
  const float4 m = ((const float4*)src)[(size_t)si * 32 + q];
  float* pd = dst + (size_t)di * 128 + q * 4;
  atomicAdd(pd + 0, m.x); atomicAdd(pd + 1, m.y); atomicAdd(pd + 2, m.z); atomicAdd(pd + 3, m.w);
}

__global__ __launch_bounds__(256) void gather3_kernel(
    const int* __restrict__ eids, int B,
    const float* __restrict__ f_src, const float* __restrict__ sum_h, const float* __restrict__ msg_new,
    float* __restrict__ fs_e, float* __restrict__ sh_e, float* __restrict__ m_e)
{
  const int g = blockIdx.x * 256 + threadIdx.x;
  const int bI = g >> 5, q = g & 31;
  if (bI >= B) return;
  const int e = eids[bI];
  ((float4*)fs_e)[(size_t)bI * 32 + q] = ((const float4*)f_src)[(size_t)e * 32 + q];
  ((float4*)sh_e)[(size_t)bI * 32 + q] = ((const float4*)sum_h)[(size_t)e * 32 + q];
  ((float4*)m_e )[(size_t)bI * 32 + q] = ((const float4*)msg_new)[(size_t)e * 32 + q];
}

// Per-graph attention over contiguous segments of n nodes; computes BOTH the
// topology-head and label-head attention in one pass over x. One wave/graph.
__global__ __launch_bounds__(64) void attn_kernel(
    const float* __restrict__ x, int n,
    const float* __restrict__ ha_d, const float* __restrict__ ha_l,
    float* __restrict__ out_d, float* __restrict__ out_l,
    int out_stride, int col_off)
{
  const int b = blockIdx.x, l = threadIdx.x;
  __shared__ __align__(16) float hd[128], hl[128];
  __shared__ float pd[64], pl[64];
  hd[l]      = ha_d[(size_t)b * 128 + l];
  hd[l + 64] = ha_d[(size_t)b * 128 + 64 + l];
  hl[l]      = ha_l[(size_t)b * 128 + l];
  hl[l + 64] = ha_l[(size_t)b * 128 + 64 + l];
  __syncthreads();
  float ed = -1e30f, el = -1e30f;
  if (l < n){
    const float4* xr = (const float4*)(x + ((size_t)b * n + l) * 128);
    float sd = 0.f, sl = 0.f;
    #pragma unroll 8
    for (int k = 0; k < 32; ++k){
      const float4 xv = xr[k];
      const float4 hdv = *(const float4*)&hd[k * 4];
      const float4 hlv = *(const float4*)&hl[k * 4];
      sd += xv.x * hdv.x + xv.y * hdv.y + xv.z * hdv.z + xv.w * hdv.w;
      sl += xv.x * hlv.x + xv.y * hlv.y + xv.z * hlv.z + xv.w * hlv.w;
    }
    ed = sd; el = sl;
  }
  const float md = wave_max64(ed), ml = wave_max64(el);
  const float exd = (l < n) ? __expf(ed - md) : 0.f;
  const float exl = (l < n) ? __expf(el - ml) : 0.f;
  const float zd = wave_sum64(exd), zl = wave_sum64(exl);
  pd[l] = exd / zd;
  pl[l] = exl / zl;
  __syncthreads();
  float od0 = 0.f, od1 = 0.f, ol0 = 0.f, ol1 = 0.f;
  for (int i = 0; i < n; ++i){
    const float* xr = x + ((size_t)b * n + i) * 128;
    const float x0 = xr[l], x1 = xr[l + 64];
    const float wd = pd[i], wl = pl[i];
    od0 += wd * x0; od1 += wd * x1;
    ol0 += wl * x0; ol1 += wl * x1;
  }
  const size_t o = (size_t)b * out_stride + col_off;
  out_d[o + l] = od0; out_d[o + 64 + l] = od1;
  out_l[o + l] = ol0; out_l[o + 64 + l] = ol1;
}

// topology CE: p = z_d @ u_d + b_d3; -mean(expand*logsig(p) + (1-expand)*logsig(1-p))
__global__ __launch_bounds__(256) void ce_topo_kernel(
    const float* __restrict__ z_d, const float* __restrict__ u_d,
    const float* __restrict__ b_d3, const float* __restrict__ expand,
    float* __restrict__ out, int B)
{
  const int r = blockIdx.x * 4 + (threadIdx.x >> 6);
  const int l = threadIdx.x & 63;
  if (r >= B) return;
  const float* row = z_d + (size_t)r * 128;
  float s = row[l] * u_d[l] + row[l + 64] * u_d[l + 64];
  s = wave_sum64(s);
  if (l == 0){
    const float p = s + b_d3[0];
    const float t = expand[r];
    const float loss = -(t * logsigf_(p) + (1.f - t) * logsigf_(1.f - p));
    atomicAdd(out, loss / (float)B);
  }
}

// label CE: q = z_l @ u_l + b_l2 (V cols); -mean(log_softmax(q)[wid])
__global__ __launch_bounds__(256) void ce_label_kernel(
    const float* __restrict__ z_l, const float* __restrict__ u_l,
    const float* __restrict__ b_l2, const int* __restrict__ wid,
    float* __restrict__ out, int B, int V)
{
  const int r = blockIdx.x, t = threadIdx.x;
  __shared__ float zrow[128];
  __shared__ float qs[1024];
  __shared__ float red[256];
  if (t < 128) zrow[t] = z_l[(size_t)r * 128 + t];
  __syncthreads();
  float q[4];
  int nj = 0;
  for (int jj = 0; jj < 4; ++jj){
    const int j = t + jj * 256;
    if (j >= V) break;
    float acc = b_l2[j];
    for (int k = 0; k < 128; ++k) acc += zrow[k] * u_l[(size_t)k * V + j];
    qs[j] = acc; q[jj] = acc; nj = jj + 1;
  }
  float mx = -1e30f;
  for (int jj = 0; jj < nj; ++jj) mx = fmaxf(mx, q[jj]);
  red[t] = mx; __syncthreads();
  for (int sgap = 128; sgap; sgap >>= 1){
    if (t < sgap) red[t] = fmaxf(red[t], red[t + sgap]);
    __syncthreads();
  }
  mx = red[0]; __syncthreads();
  float se = 0.f;
  for (int jj = 0; jj < nj; ++jj) se += __expf(q[jj] - mx);
  red[t] = se; __syncthreads();
  for (int sgap = 128; sgap; sgap >>= 1){
    if (t < sgap) red[t] += red[t + sgap];
    __syncthreads();
  }
  if (t == 0){
    const float lp = qs[wid[r]] - mx - __logf(red[0]);
    atomicAdd(out + 1, -lp / (float)B);
  }
}

extern "C" void kernel_launch(void* const* d_in, const int* in_sizes, int n_in,
                              void* d_out, int out_size, void* d_ws, size_t ws_size,
                              hipStream_t stream)
{
  const float* msg    = (const float*)d_in[0];
  const float* f_src  = (const float*)d_in[1];
  const float* f_dst  = (const float*)d_in[2];
  const float* x_T    = (const float*)d_in[3];
  const float* x_G    = (const float*)d_in[4];
  const float* expand = (const float*)d_in[5];
  const float* wz = (const float*)d_in[6];
  const float* uz = (const float*)d_in[7];
  const float* bz = (const float*)d_in[8];
  const float* wr = (const float*)d_in[9];
  const float* ur = (const float*)d_in[10];
  const float* br = (const float*)d_in[11];
  const float* w  = (const float*)d_in[12];
  const float* u  = (const float*)d_in[13];
  const float* b  = (const float*)d_in[14];
  const float* w_d1 = (const float*)d_in[15];
  const float* w_d2 = (const float*)d_in[16];
  const float* b_d1 = (const float*)d_in[17];
  const float* a_dT = (const float*)d_in[18];
  const float* a_dG = (const float*)d_in[19];
  const float* w_d3 = (const float*)d_in[20];
  const float* w_d4 = (const float*)d_in[21];
  const float* b_d2 = (const float*)d_in[22];
  const float* u_d  = (const float*)d_in[23];
  const float* b_d3 = (const float*)d_in[24];
  const float* w_l1 = (const float*)d_in[25];
  const float* w_l2 = (const float*)d_in[26];
  const float* b_l1 = (const float*)d_in[27];
  const float* a_lT = (const float*)d_in[28];
  const float* a_lG = (const float*)d_in[29];
  const float* u_l  = (const float*)d_in[30];
  const float* b_l2 = (const float*)d_in[31];
  const int* lg_src = (const int*)d_in[32];
  const int* lg_dst = (const int*)d_in[33];
  const int* eids   = (const int*)d_in[34];
  const int* wid    = (const int*)d_in[35];

  const int d = 128;
  const int E   = in_sizes[0] / d;
  const int ELG = in_sizes[32];
  const int B   = in_sizes[34];
  const int V   = in_sizes[31];
  const int nT  = (in_sizes[3] / d) / B;
  const int nG  = (in_sizes[4] / d) / B;

  const size_t EB = (size_t)E * d * sizeof(float);
  const size_t BB = (size_t)B * d * sizeof(float);
  char* p = (char*)d_ws;
  float* buf0 = (float*)p; p += EB;   // G -> R -> z
  float* buf1 = (float*)p; p += EB;   // s -> msg_new (in-place)
  float* buf2 = (float*)p; p += EB;   // srh -> sum_h (re-zeroed)
  float* fs_e = (float*)p; p += BB;
  float* sh_e = (float*)p; p += BB;
  float* m_e  = (float*)p; p += BB;
  float* h_t  = (float*)p; p += BB;
  float* haTd = (float*)p; p += BB;
  float* haGd = (float*)p; p += BB;
  float* haTl = (float*)p; p += BB;
  float* haGl = (float*)p; p += BB;
  float* c_d  = (float*)p; p += 2 * BB;
  float* c_l  = (float*)p; p += 2 * BB;
  float* z_d  = (float*)p; p += BB;
  float* z_l  = (float*)p; p += BB;

  hipMemsetAsync(buf1, 0, EB, stream);
  hipMemsetAsync(buf2, 0, EB, stream);
  hipMemsetAsync(d_out, 0, 2 * sizeof(float), stream);

  const int GB_E = E / 32, GB_B = B / 32;
  const int SCG = (ELG * 32 + 255) / 256;

  // R = sigmoid(f_dst@wr + msg@ur + br) * msg           -> buf0
  gemm128_kernel<<<GB_E, 256, 0, stream>>>(E, f_dst, 128, wr, msg, 128, ur,
                                           br, EPI_SIGMUL, msg, nullptr, buf0);
  // s += msg[lg_src], srh += R[lg_src] at lg_dst
  scatter2_kernel<<<SCG, 256, 0, stream>>>(lg_src, lg_dst, ELG, msg, buf0, buf1, buf2);
  // z = sigmoid(f_src@wz + s@uz + bz)                   -> buf0
  gemm128_kernel<<<GB_E, 256, 0, stream>>>(E, f_src, 128, wz, buf1, 128, uz,
                                           bz, EPI_SIGMOID, nullptr, nullptr, buf0);
  // msg_new = (1-z)*s + z*tanh(f_src@w + srh@u + b)     -> buf1 (in-place over s)
  gemm128_kernel<<<GB_E, 256, 0, stream>>>(E, f_src, 128, w, buf2, 128, u,
                                           b, EPI_GRUMIX, buf0, buf1, buf1);
  // sum_h = segsum(msg_new[lg_src], lg_dst)             -> buf2 (re-zeroed)
  hipMemsetAsync(buf2, 0, EB, stream);
  scatter1_kernel<<<SCG, 256, 0, stream>>>(lg_src, lg_dst, ELG, buf1, buf2);
  // gathers at eids
  gather3_kernel<<<(B * 32 + 255) / 256, 256, 0, stream>>>(eids, B, f_src, buf2, buf1,
                                                           fs_e, sh_e, m_e);
  // h_t = relu(fs_e@w_d1 + sh_e@w_d2 + b_d1)
  gemm128_kernel<<<GB_B, 256, 0, stream>>>(B, fs_e, 128, w_d1, sh_e, 128, w_d2,
                                           b_d1, EPI_RELU, nullptr, nullptr, h_t);
  // attention projections
  gemm128_kernel<<<GB_B, 256, 0, stream>>>(B, h_t, 128, a_dT, nullptr, 0, nullptr,
                                           nullptr, EPI_NONE, nullptr, nullptr, haTd);
  gemm128_kernel<<<GB_B, 256, 0, stream>>>(B, h_t, 128, a_dG, nullptr, 0, nullptr,
                                           nullptr, EPI_NONE, nullptr, nullptr, haGd);
  gemm128_kernel<<<GB_B, 256, 0, stream>>>(B, m_e, 128, a_lT, nullptr, 0, nullptr,
                                           nullptr, EPI_NONE, nullptr, nullptr, haTl);
  gemm128_kernel<<<GB_B, 256, 0, stream>>>(B, m_e, 128, a_lG, nullptr, 0, nullptr,
                                           nullptr, EPI_NONE, nullptr, nullptr, haGl);
  // fused attention (both heads share one pass over x)
  attn_kernel<<<B, 64, 0, stream>>>(x_T, nT, haTd, haTl, c_d, c_l, 2 * d, 0);
  attn_kernel<<<B, 64, 0, stream>>>(x_G, nG, haGd, haGl, c_d, c_l, 2 * d, d);
  // z_d = relu(h_t@w_d3 + c_d@w_d4 + b_d2)
  gemm128_kernel<<<GB_B, 256, 0, stream>>>(B, h_t, 128, w_d3, c_d, 256, w_d4,
                                           b_d2, EPI_RELU, nullptr, nullptr, z_d);
  // z_l = relu(m_e@w_l1 + c_l@w_l2 + b_l1)
  gemm128_kernel<<<GB_B, 256, 0, stream>>>(B, m_e, 128, w_l1, c_l, 256, w_l2,
                                           b_l1, EPI_RELU, nullptr, nullptr, z_l);
  // losses
  ce_topo_kernel<<<(B + 3) / 4, 256, 0, stream>>>(z_d, u_d, b_d3, expand, (float*)d_out, B);
  ce_label_kernel<<<B, 256, 0, stream>>>(z_l, u_l, b_l2, wid, (float*)d_out, B, V);
}

// Round 4
// 1396.364 us; speedup vs baseline: 2.6752x; 2.6752x over previous
//
#include <hip/hip_runtime.h>
#include <math.h>

// G2GDecoder forward: TreeGRU over line graph + topology/label heads.
// All f32. d=128 fixed. M of every GEMM is a multiple of 32.
// R2: segment sums via CSR gather (build CSR-by-dst once, reuse 2x) instead
// of f32 atomicAdd scatter (which caused 2 GB of L2 atomic write-backs).
// R3/R4: identical resubmits — benches died to container infra failures.

__device__ inline float wave_sum64(float v){
  #pragma unroll
  for (int m = 32; m; m >>= 1) v += __shfl_xor(v, m, 64);
  return v;
}
__device__ inline float wave_max64(float v){
  #pragma unroll
  for (int m = 32; m; m >>= 1) v = fmaxf(v, __shfl_xor(v, m, 64));
  return v;
}
__device__ inline float sigmoidf_(float x){ return 1.f / (1.f + __expf(-x)); }
__device__ inline float tanh_fast(float x){
  x = fminf(fmaxf(x, -15.f), 15.f);
  float e = __expf(2.f * x);
  return (e - 1.f) / (e + 1.f);
}
__device__ inline float logsigf_(float x){
  return (x >= 0.f) ? -log1pf(__expf(-x)) : (x - log1pf(__expf(x)));
}

enum { EPI_NONE = 0, EPI_SIGMOID = 1, EPI_RELU = 2, EPI_SIGMUL = 3, EPI_GRUMIX = 4 };

// C[M,128] = epi( A1[M,K1] @ W1[K1,128] (+ A2[M,K2] @ W2[K2,128]) + bias )
__global__ __launch_bounds__(256) void gemm128_kernel(
    int M,
    const float* __restrict__ A1, int K1, const float* __restrict__ W1,
    const float* __restrict__ A2, int K2, const float* __restrict__ W2,
    const float* __restrict__ bias, int epi,
    const float* __restrict__ aux1, const float* __restrict__ aux2,
    float* __restrict__ out)
{
  __shared__ __align__(16) float Wt[32 * 128];  // W k-tile [32][128]
  __shared__ float At[32][33];                  // A tile transposed [kk][row], +1 pad
  const int t = threadIdx.x;
  const int row0 = blockIdx.x * 32;
  const int cg = t & 31;        // col group: cols cg*4 .. cg*4+3
  const int rg = t >> 5;        // row group: rows rg*4 .. rg*4+3
  float acc[4][4] = {};

  for (int src = 0; src < 2; ++src){
    const float* A = src ? A2 : A1;
    const float* W = src ? W2 : W1;
    const int K = src ? K2 : K1;
    if (A == nullptr) break;
    for (int kt = 0; kt < K; kt += 32){
      __syncthreads();
      const float4* Wg = (const float4*)(W + (size_t)kt * 128);
      #pragma unroll
      for (int rr = 0; rr < 4; ++rr)
        ((float4*)Wt)[t + rr * 256] = Wg[t + rr * 256];
      {
        const int r = t >> 3, f4 = t & 7;
        float4 a = *(const float4*)(A + (size_t)(row0 + r) * K + kt + f4 * 4);
        At[f4 * 4 + 0][r] = a.x;
        At[f4 * 4 + 1][r] = a.y;
        At[f4 * 4 + 2][r] = a.z;
        At[f4 * 4 + 3][r] = a.w;
      }
      __syncthreads();
      #pragma unroll
      for (int kk = 0; kk < 32; ++kk){
        const float4 w4 = *(const float4*)&Wt[kk * 128 + cg * 4];
        const float a0 = At[kk][rg * 4 + 0];
        const float a1 = At[kk][rg * 4 + 1];
        const float a2 = At[kk][rg * 4 + 2];
        const float a3 = At[kk][rg * 4 + 3];
        acc[0][0] += a0 * w4.x; acc[0][1] += a0 * w4.y; acc[0][2] += a0 * w4.z; acc[0][3] += a0 * w4.w;
        acc[1][0] += a1 * w4.x; acc[1][1] += a1 * w4.y; acc[1][2] += a1 * w4.z; acc[1][3] += a1 * w4.w;
        acc[2][0] += a2 * w4.x; acc[2][1] += a2 * w4.y; acc[2][2] += a2 * w4.z; acc[2][3] += a2 * w4.w;
        acc[3][0] += a3 * w4.x; acc[3][1] += a3 * w4.y; acc[3][2] += a3 * w4.z; acc[3][3] += a3 * w4.w;
      }
    }
  }

  const int colb = cg * 4;
  float bv[4] = {0.f, 0.f, 0.f, 0.f};
  if (bias){
    #pragma unroll
    for (int j = 0; j < 4; ++j) bv[j] = bias[colb + j];
  }
  #pragma unroll
  for (int i = 0; i < 4; ++i){
    const int row = row0 + rg * 4 + i;
    const size_t o = (size_t)row * 128 + colb;
    float v[4];
    #pragma unroll
    for (int j = 0; j < 4; ++j) v[j] = acc[i][j] + bv[j];
    if (epi == EPI_SIGMOID){
      #pragma unroll
      for (int j = 0; j < 4; ++j) v[j] = sigmoidf_(v[j]);
    } else if (epi == EPI_RELU){
      #pragma unroll
      for (int j = 0; j < 4; ++j) v[j] = fmaxf(v[j], 0.f);
    } else if (epi == EPI_SIGMUL){
      const float4 m4 = *(const float4*)(aux1 + o);
      const float mm[4] = {m4.x, m4.y, m4.z, m4.w};
      #pragma unroll
      for (int j = 0; j < 4; ++j) v[j] = sigmoidf_(v[j]) * mm[j];
    } else if (epi == EPI_GRUMIX){
      const float4 z4 = *(const float4*)(aux1 + o);
      const float4 s4 = *(const float4*)(aux2 + o);
      const float zz[4] = {z4.x, z4.y, z4.z, z4.w};
      const float ss[4] = {s4.x, s4.y, s4.z, s4.w};
      #pragma unroll
      for (int j = 0; j < 4; ++j) v[j] = (1.f - zz[j]) * ss[j] + zz[j] * tanh_fast(v[j]);
    }
    *(float4*)(out + o) = make_float4(v[0], v[1], v[2], v[3]);
  }
}

// ---------------- CSR build (by lg_dst) ----------------

__global__ __launch_bounds__(256) void csr_count_kernel(
    const int* __restrict__ lg_dst, int ELG,
    int* __restrict__ cnt, int* __restrict__ ticket)
{
  const int e = blockIdx.x * 256 + threadIdx.x;
  if (e < ELG) ticket[e] = atomicAdd(&cnt[lg_dst[e]], 1);
}

#define SCAN_CHUNK 1024

__global__ __launch_bounds__(256) void scan_totals_kernel(
    const int* __restrict__ cnt, int n, int* __restrict__ bsum)
{
  __shared__ int red[256];
  const int base = blockIdx.x * SCAN_CHUNK;
  const int t = threadIdx.x;
  int s = 0;
  #pragma unroll
  for (int k = 0; k < 4; ++k){
    const int idx = base + t + k * 256;
    if (idx < n) s += cnt[idx];
  }
  red[t] = s; __syncthreads();
  for (int g = 128; g; g >>= 1){
    if (t < g) red[t] += red[t + g];
    __syncthreads();
  }
  if (t == 0) bsum[blockIdx.x] = red[0];
}

__global__ void scan_serial_kernel(int* bsum, int nb, int* offsets, int n)
{
  if (threadIdx.x == 0 && blockIdx.x == 0){
    int acc = 0;
    for (int i = 0; i < nb; ++i){ const int v = bsum[i]; bsum[i] = acc; acc += v; }
    offsets[n] = acc;
  }
}

__global__ __launch_bounds__(256) void scan_write_kernel(
    const int* __restrict__ cnt, int n,
    const int* __restrict__ bsum, int* __restrict__ offsets)
{
  __shared__ int wsum[4];
  const int base = blockIdx.x * SCAN_CHUNK;
  const int t = threadIdx.x;
  int v[4]; int lsum = 0;
  #pragma unroll
  for (int k = 0; k < 4; ++k){
    const int idx = base + t * 4 + k;
    v[k] = (idx < n) ? cnt[idx] : 0;
    lsum += v[k];
  }
  const int lane = t & 63, wv = t >> 6;
  int x = lsum;
  #pragma unroll
  for (int off = 1; off < 64; off <<= 1){
    const int y = __shfl_up(x, off, 64);
    if (lane >= off) x += y;
  }
  if (lane == 63) wsum[wv] = x;
  __syncthreads();
  int woff = 0;
  for (int i = 0; i < wv; ++i) woff += wsum[i];
  int run = x - lsum + woff + bsum[blockIdx.x];
  #pragma unroll
  for (int k = 0; k < 4; ++k){
    const int idx = base + t * 4 + k;
    if (idx < n) offsets[idx] = run;
    run += v[k];
  }
}

__global__ __launch_bounds__(256) void csr_fill_kernel(
    const int* __restrict__ lg_src, const int* __restrict__ lg_dst,
    const int* __restrict__ ticket, int ELG,
    const int* __restrict__ offsets, int* __restrict__ csr_src)
{
  const int e = blockIdx.x * 256 + threadIdx.x;
  if (e >= ELG) return;
  csr_src[offsets[lg_dst[e]] + ticket[e]] = lg_src[e];
}

// ---------------- CSR gathers (one write per dst row) ----------------

// s[i] = sum msg[src], srh[i] = sum R[src] over incoming edges of i
__global__ __launch_bounds__(256) void gather2_csr_kernel(
    const int* __restrict__ offsets, const int* __restrict__ csr_src, int E,
    const float* __restrict__ msg, const float* __restrict__ R,
    float* __restrict__ s, float* __restrict__ srh)
{
  const int g = blockIdx.x * 256 + threadIdx.x;
  const int row = g >> 5, q = g & 31;
  if (row >= E) return;
  const int beg = offsets[row], end = offsets[row + 1];
  float4 a = make_float4(0.f, 0.f, 0.f, 0.f);
  float4 c = make_float4(0.f, 0.f, 0.f, 0.f);
  for (int j = beg; j < end; ++j){
    const int si = csr_src[j];
    const float4 m = ((const float4*)msg)[(size_t)si * 32 + q];
    const float4 r = ((const float4*)R)[(size_t)si * 32 + q];
    a.x += m.x; a.y += m.y; a.z += m.z; a.w += m.w;
    c.x += r.x; c.y += r.y; c.z += r.z; c.w += r.w;
  }
  ((float4*)s)[(size_t)row * 32 + q] = a;
  ((float4*)srh)[(size_t)row * 32 + q] = c;
}

__global__ __launch_bounds__(256) void gather1_csr_kernel(
    const int* __restrict__ offsets, const int* __restrict__ csr_src, int E,
    const float* __restrict__ src, float* __restrict__ dst)
{
  const int g = blockIdx.x * 256 + threadIdx.x;
  const int row = g >> 5, q = g & 31;
  if (row >= E) return;
  const int beg = offsets[row], end = offsets[row + 1];
  float4 a = make_float4(0.f, 0.f, 0.f, 0.f);
  for (int j = beg; j < end; ++j){
    const int si = csr_src[j];
    const float4 m = ((const float4*)src)[(size_t)si * 32 + q];
    a.x += m.x; a.y += m.y; a.z += m.z; a.w += m.w;
  }
  ((float4*)dst)[(size_t)row * 32 + q] = a;
}

__global__ __launch_bounds__(256) void gather3_kernel(
    const int* __restrict__ eids, int B,
    const float* __restrict__ f_src, const float* __restrict__ sum_h, const float* __restrict__ msg_new,
    float* __restrict__ fs_e, float* __restrict__ sh_e, float* __restrict__ m_e)
{
  const int g = blockIdx.x * 256 + threadIdx.x;
  const int bI = g >> 5, q = g & 31;
  if (bI >= B) return;
  const int e = eids[bI];
  ((float4*)fs_e)[(size_t)bI * 32 + q] = ((const float4*)f_src)[(size_t)e * 32 + q];
  ((float4*)sh_e)[(size_t)bI * 32 + q] = ((const float4*)sum_h)[(size_t)e * 32 + q];
  ((float4*)m_e )[(size_t)bI * 32 + q] = ((const float4*)msg_new)[(size_t)e * 32 + q];
}

// Per-graph attention over contiguous segments of n nodes; both heads fused.
__global__ __launch_bounds__(64) void attn_kernel(
    const float* __restrict__ x, int n,
    const float* __restrict__ ha_d, const float* __restrict__ ha_l,
    float* __restrict__ out_d, float* __restrict__ out_l,
    int out_stride, int col_off)
{
  const int b = blockIdx.x, l = threadIdx.x;
  __shared__ __align__(16) float hd[128], hl[128];
  __shared__ float pd[64], pl[64];
  hd[l]      = ha_d[(size_t)b * 128 + l];
  hd[l + 64] = ha_d[(size_t)b * 128 + 64 + l];
  hl[l]      = ha_l[(size_t)b * 128 + l];
  hl[l + 64] = ha_l[(size_t)b * 128 + 64 + l];
  __syncthreads();
  float ed = -1e30f, el = -1e30f;
  if (l < n){
    const float4* xr = (const float4*)(x + ((size_t)b * n + l) * 128);
    float sd = 0.f, sl = 0.f;
    #pragma unroll 8
    for (int k = 0; k < 32; ++k){
      const float4 xv = xr[k];
      const float4 hdv = *(const float4*)&hd[k * 4];
      const float4 hlv = *(const float4*)&hl[k * 4];
      sd += xv.x * hdv.x + xv.y * hdv.y + xv.z * hdv.z + xv.w * hdv.w;
      sl += xv.x * hlv.x + xv.y * hlv.y + xv.z * hlv.z + xv.w * hlv.w;
    }
    ed = sd; el = sl;
  }
  const float md = wave_max64(ed), ml = wave_max64(el);
  const float exd = (l < n) ? __expf(ed - md) : 0.f;
  const float exl = (l < n) ? __expf(el - ml) : 0.f;
  const float zd = wave_sum64(exd), zl = wave_sum64(exl);
  pd[l] = exd / zd;
  pl[l] = exl / zl;
  __syncthreads();
  float od0 = 0.f, od1 = 0.f, ol0 = 0.f, ol1 = 0.f;
  for (int i = 0; i < n; ++i){
    const float* xr = x + ((size_t)b * n + i) * 128;
    const float x0 = xr[l], x1 = xr[l + 64];
    const float wd = pd[i], wl = pl[i];
    od0 += wd * x0; od1 += wd * x1;
    ol0 += wl * x0; ol1 += wl * x1;
  }
  const size_t o = (size_t)b * out_stride + col_off;
  out_d[o + l] = od0; out_d[o + 64 + l] = od1;
  out_l[o + l] = ol0; out_l[o + 64 + l] = ol1;
}

__global__ __launch_bounds__(256) void ce_topo_kernel(
    const float* __restrict__ z_d, const float* __restrict__ u_d,
    const float* __restrict__ b_d3, const float* __restrict__ expand,
    float* __restrict__ out, int B)
{
  const int r = blockIdx.x * 4 + (threadIdx.x >> 6);
  const int l = threadIdx.x & 63;
  if (r >= B) return;
  const float* row = z_d + (size_t)r * 128;
  float s = row[l] * u_d[l] + row[l + 64] * u_d[l + 64];
  s = wave_sum64(s);
  if (l == 0){
    const float p = s + b_d3[0];
    const float t = expand[r];
    const float loss = -(t * logsigf_(p) + (1.f - t) * logsigf_(1.f - p));
    atomicAdd(out, loss / (float)B);
  }
}

__global__ __launch_bounds__(256) void ce_label_kernel(
    const float* __restrict__ z_l, const float* __restrict__ u_l,
    const float* __restrict__ b_l2, const int* __restrict__ wid,
    float* __restrict__ out, int B, int V)
{
  const int r = blockIdx.x, t = threadIdx.x;
  __shared__ float zrow[128];
  __shared__ float qs[1024];
  __shared__ float red[256];
  if (t < 128) zrow[t] = z_l[(size_t)r * 128 + t];
  __syncthreads();
  float q[4];
  int nj = 0;
  for (int jj = 0; jj < 4; ++jj){
    const int j = t + jj * 256;
    if (j >= V) break;
    float acc = b_l2[j];
    for (int k = 0; k < 128; ++k) acc += zrow[k] * u_l[(size_t)k * V + j];
    qs[j] = acc; q[jj] = acc; nj = jj + 1;
  }
  float mx = -1e30f;
  for (int jj = 0; jj < nj; ++jj) mx = fmaxf(mx, q[jj]);
  red[t] = mx; __syncthreads();
  for (int sgap = 128; sgap; sgap >>= 1){
    if (t < sgap) red[t] = fmaxf(red[t], red[t + sgap]);
    __syncthreads();
  }
  mx = red[0]; __syncthreads();
  float se = 0.f;
  for (int jj = 0; jj < nj; ++jj) se += __expf(q[jj] - mx);
  red[t] = se; __syncthreads();
  for (int sgap = 128; sgap; sgap >>= 1){
    if (t < sgap) red[t] += red[t + sgap];
    __syncthreads();
  }
  if (t == 0){
    const float lp = qs[wid[r]] - mx - __logf(red[0]);
    atomicAdd(out + 1, -lp / (float)B);
  }
}

extern "C" void kernel_launch(void* const* d_in, const int* in_sizes, int n_in,
                              void* d_out, int out_size, void* d_ws, size_t ws_size,
                              hipStream_t stream)
{
  const float* msg    = (const float*)d_in[0];
  const float* f_src  = (const float*)d_in[1];
  const float* f_dst  = (const float*)d_in[2];
  const float* x_T    = (const float*)d_in[3];
  const float* x_G    = (const float*)d_in[4];
  const float* expand = (const float*)d_in[5];
  const float* wz = (const float*)d_in[6];
  const float* uz = (const float*)d_in[7];
  const float* bz = (const float*)d_in[8];
  const float* wr = (const float*)d_in[9];
  const float* ur = (const float*)d_in[10];
  const float* br = (const float*)d_in[11];
  const float* w  = (const float*)d_in[12];
  const float* u  = (const float*)d_in[13];
  const float* b  = (const float*)d_in[14];
  const float* w_d1 = (const float*)d_in[15];
  const float* w_d2 = (const float*)d_in[16];
  const float* b_d1 = (const float*)d_in[17];
  const float* a_dT = (const float*)d_in[18];
  const float* a_dG = (const float*)d_in[19];
  const float* w_d3 = (const float*)d_in[20];
  const float* w_d4 = (const float*)d_in[21];
  const float* b_d2 = (const float*)d_in[22];
  const float* u_d  = (const float*)d_in[23];
  const float* b_d3 = (const float*)d_in[24];
  const float* w_l1 = (const float*)d_in[25];
  const float* w_l2 = (const float*)d_in[26];
  const float* b_l1 = (const float*)d_in[27];
  const float* a_lT = (const float*)d_in[28];
  const float* a_lG = (const float*)d_in[29];
  const float* u_l  = (const float*)d_in[30];
  const float* b_l2 = (const float*)d_in[31];
  const int* lg_src = (const int*)d_in[32];
  const int* lg_dst = (const int*)d_in[33];
  const int* eids   = (const int*)d_in[34];
  const int* wid    = (const int*)d_in[35];

  const int d = 128;
  const int E   = in_sizes[0] / d;
  const int ELG = in_sizes[32];
  const int B   = in_sizes[34];
  const int V   = in_sizes[31];
  const int nT  = (in_sizes[3] / d) / B;
  const int nG  = (in_sizes[4] / d) / B;

  const size_t EB = (size_t)E * d * sizeof(float);
  const size_t BB = (size_t)B * d * sizeof(float);
  char* p = (char*)d_ws;
  float* buf0 = (float*)p; p += EB;   // R -> z
  float* buf1 = (float*)p; p += EB;   // s -> msg_new (in-place)
  float* buf2 = (float*)p; p += EB;   // srh -> sum_h
  float* fs_e = (float*)p; p += BB;
  float* sh_e = (float*)p; p += BB;
  float* m_e  = (float*)p; p += BB;
  float* h_t  = (float*)p; p += BB;
  float* haTd = (float*)p; p += BB;
  float* haGd = (float*)p; p += BB;
  float* haTl = (float*)p; p += BB;
  float* haGl = (float*)p; p += BB;
  float* c_d  = (float*)p; p += 2 * BB;
  float* c_l  = (float*)p; p += 2 * BB;
  float* z_d  = (float*)p; p += BB;
  float* z_l  = (float*)p; p += BB;
  // CSR scratch
  int* cnt     = (int*)p; p += (size_t)E * sizeof(int);
  int* offsets = (int*)p; p += (size_t)(E + 1) * sizeof(int);
  int* ticket  = (int*)p; p += (size_t)ELG * sizeof(int);
  int* csr_src = (int*)p; p += (size_t)ELG * sizeof(int);
  int* bsum    = (int*)p; p += (size_t)((E + SCAN_CHUNK - 1) / SCAN_CHUNK + 1) * sizeof(int);

  hipMemsetAsync(cnt, 0, (size_t)E * sizeof(int), stream);
  hipMemsetAsync(d_out, 0, 2 * sizeof(float), stream);

  const int GB_E = E / 32, GB_B = B / 32;
  const int nb = (E + SCAN_CHUNK - 1) / SCAN_CHUNK;
  const int GROW = (E * 32 + 255) / 256;

  // ---- CSR build (by lg_dst), reused for both segment sums ----
  csr_count_kernel<<<(ELG + 255) / 256, 256, 0, stream>>>(lg_dst, ELG, cnt, ticket);
  scan_totals_kernel<<<nb, 256, 0, stream>>>(cnt, E, bsum);
  scan_serial_kernel<<<1, 64, 0, stream>>>(bsum, nb, offsets, E);
  scan_write_kernel<<<nb, 256, 0, stream>>>(cnt, E, bsum, offsets);
  csr_fill_kernel<<<(ELG + 255) / 256, 256, 0, stream>>>(lg_src, lg_dst, ticket, ELG, offsets, csr_src);

  // R = sigmoid(f_dst@wr + msg@ur + br) * msg           -> buf0
  gemm128_kernel<<<GB_E, 256, 0, stream>>>(E, f_dst, 128, wr, msg, 128, ur,
                                           br, EPI_SIGMUL, msg, nullptr, buf0);
  // s = segsum(msg), srh = segsum(R)                    -> buf1, buf2
  gather2_csr_kernel<<<GROW, 256, 0, stream>>>(offsets, csr_src, E, msg, buf0, buf1, buf2);
  // z = sigmoid(f_src@wz + s@uz + bz)                   -> buf0
  gemm128_kernel<<<GB_E, 256, 0, stream>>>(E, f_src, 128, wz, buf1, 128, uz,
                                           bz, EPI_SIGMOID, nullptr, nullptr, buf0);
  // msg_new = (1-z)*s + z*tanh(f_src@w + srh@u + b)     -> buf1 (in-place over s)
  gemm128_kernel<<<GB_E, 256, 0, stream>>>(E, f_src, 128, w, buf2, 128, u,
                                           b, EPI_GRUMIX, buf0, buf1, buf1);
  // sum_h = segsum(msg_new)                             -> buf2
  gather1_csr_kernel<<<GROW, 256, 0, stream>>>(offsets, csr_src, E, buf1, buf2);
  // gathers at eids
  gather3_kernel<<<(B * 32 + 255) / 256, 256, 0, stream>>>(eids, B, f_src, buf2, buf1,
                                                           fs_e, sh_e, m_e);
  // h_t = relu(fs_e@w_d1 + sh_e@w_d2 + b_d1)
  gemm128_kernel<<<GB_B, 256, 0, stream>>>(B, fs_e, 128, w_d1, sh_e, 128, w_d2,
                                           b_d1, EPI_RELU, nullptr, nullptr, h_t);
  // attention projections
  gemm128_kernel<<<GB_B, 256, 0, stream>>>(B, h_t, 128, a_dT, nullptr, 0, nullptr,
                                           nullptr, EPI_NONE, nullptr, nullptr, haTd);
  gemm128_kernel<<<GB_B, 256, 0, stream>>>(B, h_t, 128, a_dG, nullptr, 0, nullptr,
                                           nullptr, EPI_NONE, nullptr, nullptr, haGd);
  gemm128_kernel<<<GB_B, 256, 0, stream>>>(B, m_e, 128, a_lT, nullptr, 0, nullptr,
                                           nullptr, EPI_NONE, nullptr, nullptr, haTl);
  gemm128_kernel<<<GB_B, 256, 0, stream>>>(B, m_e, 128, a_lG, nullptr, 0, nullptr,
                                           nullptr, EPI_NONE, nullptr, nullptr, haGl);
  // fused attention (both heads share one pass over x)
  attn_kernel<<<B, 64, 0, stream>>>(x_T, nT, haTd, haTl, c_d, c_l, 2 * d, 0);
  attn_kernel<<<B, 64, 0, stream>>>(x_G, nG, haGd, haGl, c_d, c_l, 2 * d, d);
  // z_d = relu(h_t@w_d3 + c_d@w_d4 + b_d2)
  gemm128_kernel<<<GB_B, 256, 0, stream>>>(B, h_t, 128, w_d3, c_d, 256, w_d4,
                                           b_d2, EPI_RELU, nullptr, nullptr, z_d);
  // z_l = relu(m_e@w_l1 + c_l@w_l2 + b_l1)
  gemm128_kernel<<<GB_B, 256, 0, stream>>>(B, m_e, 128, w_l1, c_l, 256, w_l2,
                                           b_l1, EPI_RELU, nullptr, nullptr, z_l);
  // losses
  ce_topo_kernel<<<(B + 3) / 4, 256, 0, stream>>>(z_d, u_d, b_d3, expand, (float*)d_out, B);
  ce_label_kernel<<<B, 256, 0, stream>>>(z_l, u_l, b_l2, wid, (float*)d_out, B, V);
}

// Round 5
// 1020.072 us; speedup vs baseline: 3.6621x; 1.3689x over previous
//
#include <hip/hip_runtime.h>
#include <math.h>

// G2GDecoder forward: TreeGRU over line graph + topology/label heads.
// R2: CSR-gather segment sums (replaced 2 GB of atomic write-backs).
// R5: all GEMMs via bf16 MFMA (16x16x32). Weights pre-converted+transposed
// to bf16 [col][k] by wprep_kernel; activations converted f32->bf16 while
// staging to LDS. fp32 GEMM removed (VALU-bound at 66% VALUBusy, 0 Mfma).

using bf16x8 = __attribute__((ext_vector_type(8))) short;
using f32x4  = __attribute__((ext_vector_type(4))) float;

__device__ inline float wave_sum64(float v){
  #pragma unroll
  for (int m = 32; m; m >>= 1) v += __shfl_xor(v, m, 64);
  return v;
}
__device__ inline float wave_max64(float v){
  #pragma unroll
  for (int m = 32; m; m >>= 1) v = fmaxf(v, __shfl_xor(v, m, 64));
  return v;
}
__device__ inline float sigmoidf_(float x){ return 1.f / (1.f + __expf(-x)); }
__device__ inline float tanh_fast(float x){
  x = fminf(fmaxf(x, -15.f), 15.f);
  float e = __expf(2.f * x);
  return (e - 1.f) / (e + 1.f);
}
__device__ inline float logsigf_(float x){
  return (x >= 0.f) ? -log1pf(__expf(-x)) : (x - log1pf(__expf(x)));
}
__device__ inline short f2bf(float f){
  union { float f; unsigned u; } v; v.f = f;
  const unsigned r = v.u + 0x7FFF + ((v.u >> 16) & 1);   // round-to-nearest-even
  return (short)(r >> 16);
}
__device__ inline unsigned pk2(short a, short b){
  return (unsigned)(unsigned short)a | ((unsigned)(unsigned short)b << 16);
}

enum { EPI_NONE = 0, EPI_SIGMOID = 1, EPI_RELU = 2, EPI_SIGMUL = 3, EPI_GRUMIX = 4 };

// ---------------- weight prep: f32 [k][col] -> bf16 Wt [col][Ktot] ----------------
// matrix table: {src1,K1,src2,K2,Ktot,dst_off(shorts)}
__global__ __launch_bounds__(256) void wprep_kernel(
    const float* wr, const float* ur, const float* wz, const float* uz,
    const float* w,  const float* u,  const float* w_d1, const float* w_d2,
    const float* a_dT, const float* a_dG, const float* a_lT, const float* a_lG,
    const float* w_d3, const float* w_d4, const float* w_l1, const float* w_l2,
    short* __restrict__ wt)
{
  const int m = blockIdx.y;
  const float* s1; const float* s2; int K1, Ktot; size_t off;
  switch (m){
    case 0: s1 = wr;   s2 = ur;   K1 = 128; Ktot = 256; off = 0;      break;
    case 1: s1 = wz;   s2 = uz;   K1 = 128; Ktot = 256; off = 32768;  break;
    case 2: s1 = w;    s2 = u;    K1 = 128; Ktot = 256; off = 65536;  break;
    case 3: s1 = w_d1; s2 = w_d2; K1 = 128; Ktot = 256; off = 98304;  break;
    case 4: s1 = a_dT; s2 = nullptr; K1 = 128; Ktot = 128; off = 131072; break;
    case 5: s1 = a_dG; s2 = nullptr; K1 = 128; Ktot = 128; off = 147456; break;
    case 6: s1 = a_lT; s2 = nullptr; K1 = 128; Ktot = 128; off = 163840; break;
    case 7: s1 = a_lG; s2 = nullptr; K1 = 128; Ktot = 128; off = 180224; break;
    case 8: s1 = w_d3; s2 = w_d4; K1 = 128; Ktot = 384; off = 196608; break;
    default:s1 = w_l1; s2 = w_l2; K1 = 128; Ktot = 384; off = 245760; break;
  }
  const int tid = blockIdx.x * 256 + threadIdx.x;
  if (tid >= 16 * Ktot) return;           // (Ktot/8)*128 threads
  const int col = tid & 127, k8 = tid >> 7;
  short v[8];
  #pragma unroll
  for (int i = 0; i < 8; ++i){
    const int k = k8 * 8 + i;
    const float* s = (k < K1) ? (s1 + (size_t)k * 128 + col)
                              : (s2 + (size_t)(k - K1) * 128 + col);
    v[i] = f2bf(*s);
  }
  uint4 pk;
  pk.x = pk2(v[0], v[1]); pk.y = pk2(v[2], v[3]);
  pk.z = pk2(v[4], v[5]); pk.w = pk2(v[6], v[7]);
  *(uint4*)&wt[off + (size_t)col * Ktot + k8 * 8] = pk;
}

// ---------------- bf16 MFMA GEMM ----------------
// C[M,128] = epi( A1[M,K1]@W1 + A2[M,K2]@W2 + bias ), Wt bf16 [128 cols][Ktot]
// A* are f32 row-major, converted to bf16 during LDS staging. M % 64 == 0.
// Block: 256 thr = 4 waves; tile 64 rows x 128 cols; wave wv owns rows wv*16..+16.
__global__ __launch_bounds__(256) void mfma_gemm_kernel(
    int M,
    const float* __restrict__ A1, int K1,
    const float* __restrict__ A2, int K2,
    const short* __restrict__ Wt, int Ktot,
    const float* __restrict__ bias, int epi,
    const float* __restrict__ aux1, const float* __restrict__ aux2,
    float* __restrict__ out)
{
  __shared__ short A_lds[64 * 40];    // 32 k + 8 pad (breaks 64B-stride bank aliasing)
  __shared__ short W_lds[128 * 40];
  const int t = threadIdx.x;
  const int row0 = blockIdx.x * 64;
  const int wv = t >> 6, lane = t & 63;
  const int l15 = lane & 15, l4 = lane >> 4;
  const int sa_row = t >> 2, sa_q = t & 3;   // A staging: 64 rows x 4 octets of 8 floats
  const int sw_col = t >> 1, sw_h = t & 1;   // W staging: 128 cols x 2 halves of 16 bf16

  f32x4 acc[8];
  #pragma unroll
  for (int n = 0; n < 8; ++n) acc[n] = (f32x4){0.f, 0.f, 0.f, 0.f};

  for (int kt = 0; kt < Ktot; kt += 32){
    const float* As; int Ks, kl;
    if (kt < K1){ As = A1; Ks = K1; kl = kt; }
    else        { As = A2; Ks = K2; kl = kt - K1; }
    // issue global loads first
    const float* asrc = As + (size_t)(row0 + sa_row) * Ks + kl + sa_q * 8;
    const float4 x0 = *(const float4*)(asrc);
    const float4 x1 = *(const float4*)(asrc + 4);
    const uint4* wsrc = (const uint4*)(Wt + (size_t)sw_col * Ktot + kt + sw_h * 16);
    const uint4 w0 = wsrc[0];
    const uint4 w1 = wsrc[1];
    uint4 pa;
    pa.x = pk2(f2bf(x0.x), f2bf(x0.y)); pa.y = pk2(f2bf(x0.z), f2bf(x0.w));
    pa.z = pk2(f2bf(x1.x), f2bf(x1.y)); pa.w = pk2(f2bf(x1.z), f2bf(x1.w));
    __syncthreads();  // previous iteration's MFMA reads done
    *(uint4*)&A_lds[sa_row * 40 + sa_q * 8] = pa;
    *(uint4*)&W_lds[sw_col * 40 + sw_h * 16 + 0] = w0;
    *(uint4*)&W_lds[sw_col * 40 + sw_h * 16 + 8] = w1;
    __syncthreads();
    // A frag: row = l15 (+wave base), k = l4*8 + j
    const bf16x8 a = *(const bf16x8*)&A_lds[(wv * 16 + l15) * 40 + l4 * 8];
    #pragma unroll
    for (int n = 0; n < 8; ++n){
      const bf16x8 bfr = *(const bf16x8*)&W_lds[(n * 16 + l15) * 40 + l4 * 8];
      acc[n] = __builtin_amdgcn_mfma_f32_16x16x32_bf16(a, bfr, acc[n], 0, 0, 0);
    }
  }

  // epilogue: C/D layout col=lane&15, row=(lane>>4)*4+reg
  #pragma unroll
  for (int n = 0; n < 8; ++n){
    const int col = n * 16 + l15;
    const float bv = bias ? bias[col] : 0.f;
    #pragma unroll
    for (int i = 0; i < 4; ++i){
      const int grow = row0 + wv * 16 + l4 * 4 + i;
      const size_t o = (size_t)grow * 128 + col;
      float v = acc[n][i] + bv;
      if (epi == EPI_SIGMOID)      v = sigmoidf_(v);
      else if (epi == EPI_RELU)    v = fmaxf(v, 0.f);
      else if (epi == EPI_SIGMUL)  v = sigmoidf_(v) * aux1[o];
      else if (epi == EPI_GRUMIX){
        const float zz = aux1[o], ss = aux2[o];
        v = (1.f - zz) * ss + zz * tanh_fast(v);
      }
      out[o] = v;
    }
  }
}

// ---------------- CSR build (by lg_dst) ----------------

__global__ __launch_bounds__(256) void csr_count_kernel(
    const int* __restrict__ lg_dst, int ELG,
    int* __restrict__ cnt, int* __restrict__ ticket)
{
  const int e = blockIdx.x * 256 + threadIdx.x;
  if (e < ELG) ticket[e] = atomicAdd(&cnt[lg_dst[e]], 1);
}

#define SCAN_CHUNK 1024

__global__ __launch_bounds__(256) void scan_totals_kernel(
    const int* __restrict__ cnt, int n, int* __restrict__ bsum)
{
  __shared__ int red[256];
  const int base = blockIdx.x * SCAN_CHUNK;
  const int t = threadIdx.x;
  int s = 0;
  #pragma unroll
  for (int k = 0; k < 4; ++k){
    const int idx = base + t + k * 256;
    if (idx < n) s += cnt[idx];
  }
  red[t] = s; __syncthreads();
  for (int g = 128; g; g >>= 1){
    if (t < g) red[t] += red[t + g];
    __syncthreads();
  }
  if (t == 0) bsum[blockIdx.x] = red[0];
}

__global__ void scan_serial_kernel(int* bsum, int nb, int* offsets, int n)
{
  if (threadIdx.x == 0 && blockIdx.x == 0){
    int acc = 0;
    for (int i = 0; i < nb; ++i){ const int v = bsum[i]; bsum[i] = acc; acc += v; }
    offsets[n] = acc;
  }
}

__global__ __launch_bounds__(256) void scan_write_kernel(
    const int* __restrict__ cnt, int n,
    const int* __restrict__ bsum, int* __restrict__ offsets)
{
  __shared__ int wsum[4];
  const int base = blockIdx.x * SCAN_CHUNK;
  const int t = threadIdx.x;
  int v[4]; int lsum = 0;
  #pragma unroll
  for (int k = 0; k < 4; ++k){
    const int idx = base + t * 4 + k;
    v[k] = (idx < n) ? cnt[idx] : 0;
    lsum += v[k];
  }
  const int lane = t & 63, wv = t >> 6;
  int x = lsum;
  #pragma unroll
  for (int off = 1; off < 64; off <<= 1){
    const int y = __shfl_up(x, off, 64);
    if (lane >= off) x += y;
  }
  if (lane == 63) wsum[wv] = x;
  __syncthreads();
  int woff = 0;
  for (int i = 0; i < wv; ++i) woff += wsum[i];
  int run = x - lsum + woff + bsum[blockIdx.x];
  #pragma unroll
  for (int k = 0; k < 4; ++k){
    const int idx = base + t * 4 + k;
    if (idx < n) offsets[idx] = run;
    run += v[k];
  }
}

__global__ __launch_bounds__(256) void csr_fill_kernel(
    const int* __restrict__ lg_src, const int* __restrict__ lg_dst,
    const int* __restrict__ ticket, int ELG,
    const int* __restrict__ offsets, int* __restrict__ csr_src)
{
  const int e = blockIdx.x * 256 + threadIdx.x;
  if (e >= ELG) return;
  csr_src[offsets[lg_dst[e]] + ticket[e]] = lg_src[e];
}

// ---------------- CSR gathers (one write per dst row) ----------------

__global__ __launch_bounds__(256) void gather2_csr_kernel(
    const int* __restrict__ offsets, const int* __restrict__ csr_src, int E,
    const float* __restrict__ msg, const float* __restrict__ R,
    float* __restrict__ s, float* __restrict__ srh)
{
  const int g = blockIdx.x * 256 + threadIdx.x;
  const int row = g >> 5, q = g & 31;
  if (row >= E) return;
  const int beg = offsets[row], end = offsets[row + 1];
  float4 a = make_float4(0.f, 0.f, 0.f, 0.f);
  float4 c = make_float4(0.f, 0.f, 0.f, 0.f);
  for (int j = beg; j < end; ++j){
    const int si = csr_src[j];
    const float4 m = ((const float4*)msg)[(size_t)si * 32 + q];
    const float4 r = ((const float4*)R)[(size_t)si * 32 + q];
    a.x += m.x; a.y += m.y; a.z += m.z; a.w += m.w;
    c.x += r.x; c.y += r.y; c.z += r.z; c.w += r.w;
  }
  ((float4*)s)[(size_t)row * 32 + q] = a;
  ((float4*)srh)[(size_t)row * 32 + q] = c;
}

__global__ __launch_bounds__(256) void gather1_csr_kernel(
    const int* __restrict__ offsets, const int* __restrict__ csr_src, int E,
    const float* __restrict__ src, float* __restrict__ dst)
{
  const int g = blockIdx.x * 256 + threadIdx.x;
  const int row = g >> 5, q = g & 31;
  if (row >= E) return;
  const int beg = offsets[row], end = offsets[row + 1];
  float4 a = make_float4(0.f, 0.f, 0.f, 0.f);
  for (int j = beg; j < end; ++j){
    const int si = csr_src[j];
    const float4 m = ((const float4*)src)[(size_t)si * 32 + q];
    a.x += m.x; a.y += m.y; a.z += m.z; a.w += m.w;
  }
  ((float4*)dst)[(size_t)row * 32 + q] = a;
}

__global__ __launch_bounds__(256) void gather3_kernel(
    const int* __restrict__ eids, int B,
    const float* __restrict__ f_src, const float* __restrict__ sum_h, const float* __restrict__ msg_new,
    float* __restrict__ fs_e, float* __restrict__ sh_e, float* __restrict__ m_e)
{
  const int g = blockIdx.x * 256 + threadIdx.x;
  const int bI = g >> 5, q = g & 31;
  if (bI >= B) return;
  const int e = eids[bI];
  ((float4*)fs_e)[(size_t)bI * 32 + q] = ((const float4*)f_src)[(size_t)e * 32 + q];
  ((float4*)sh_e)[(size_t)bI * 32 + q] = ((const float4*)sum_h)[(size_t)e * 32 + q];
  ((float4*)m_e )[(size_t)bI * 32 + q] = ((const float4*)msg_new)[(size_t)e * 32 + q];
}

// Per-graph attention over contiguous segments of n nodes; both heads fused.
__global__ __launch_bounds__(64) void attn_kernel(
    const float* __restrict__ x, int n,
    const float* __restrict__ ha_d, const float* __restrict__ ha_l,
    float* __restrict__ out_d, float* __restrict__ out_l,
    int out_stride, int col_off)
{
  const int b = blockIdx.x, l = threadIdx.x;
  __shared__ __align__(16) float hd[128], hl[128];
  __shared__ float pd[64], pl[64];
  hd[l]      = ha_d[(size_t)b * 128 + l];
  hd[l + 64] = ha_d[(size_t)b * 128 + 64 + l];
  hl[l]      = ha_l[(size_t)b * 128 + l];
  hl[l + 64] = ha_l[(size_t)b * 128 + 64 + l];
  __syncthreads();
  float ed = -1e30f, el = -1e30f;
  if (l < n){
    const float4* xr = (const float4*)(x + ((size_t)b * n + l) * 128);
    float sd = 0.f, sl = 0.f;
    #pragma unroll 8
    for (int k = 0; k < 32; ++k){
      const float4 xv = xr[k];
      const float4 hdv = *(const float4*)&hd[k * 4];
      const float4 hlv = *(const float4*)&hl[k * 4];
      sd += xv.x * hdv.x + xv.y * hdv.y + xv.z * hdv.z + xv.w * hdv.w;
      sl += xv.x * hlv.x + xv.y * hlv.y + xv.z * hlv.z + xv.w * hlv.w;
    }
    ed = sd; el = sl;
  }
  const float md = wave_max64(ed), ml = wave_max64(el);
  const float exd = (l < n) ? __expf(ed - md) : 0.f;
  const float exl = (l < n) ? __expf(el - ml) : 0.f;
  const float zd = wave_sum64(exd), zl = wave_sum64(exl);
  pd[l] = exd / zd;
  pl[l] = exl / zl;
  __syncthreads();
  float od0 = 0.f, od1 = 0.f, ol0 = 0.f, ol1 = 0.f;
  for (int i = 0; i < n; ++i){
    const float* xr = x + ((size_t)b * n + i) * 128;
    const float x0 = xr[l], x1 = xr[l + 64];
    const float wd = pd[i], wl = pl[i];
    od0 += wd * x0; od1 += wd * x1;
    ol0 += wl * x0; ol1 += wl * x1;
  }
  const size_t o = (size_t)b * out_stride + col_off;
  out_d[o + l] = od0; out_d[o + 64 + l] = od1;
  out_l[o + l] = ol0; out_l[o + 64 + l] = ol1;
}

__global__ __launch_bounds__(256) void ce_topo_kernel(
    const float* __restrict__ z_d, const float* __restrict__ u_d,
    const float* __restrict__ b_d3, const float* __restrict__ expand,
    float* __restrict__ out, int B)
{
  const int r = blockIdx.x * 4 + (threadIdx.x >> 6);
  const int l = threadIdx.x & 63;
  if (r >= B) return;
  const float* row = z_d + (size_t)r * 128;
  float s = row[l] * u_d[l] + row[l + 64] * u_d[l + 64];
  s = wave_sum64(s);
  if (l == 0){
    const float p = s + b_d3[0];
    const float t = expand[r];
    const float loss = -(t * logsigf_(p) + (1.f - t) * logsigf_(1.f - p));
    atomicAdd(out, loss / (float)B);
  }
}

__global__ __launch_bounds__(256) void ce_label_kernel(
    const float* __restrict__ z_l, const float* __restrict__ u_l,
    const float* __restrict__ b_l2, const int* __restrict__ wid,
    float* __restrict__ out, int B, int V)
{
  const int r = blockIdx.x, t = threadIdx.x;
  __shared__ float zrow[128];
  __shared__ float qs[1024];
  __shared__ float red[256];
  if (t < 128) zrow[t] = z_l[(size_t)r * 128 + t];
  __syncthreads();
  float q[4];
  int nj = 0;
  for (int jj = 0; jj < 4; ++jj){
    const int j = t + jj * 256;
    if (j >= V) break;
    float acc = b_l2[j];
    for (int k = 0; k < 128; ++k) acc += zrow[k] * u_l[(size_t)k * V + j];
    qs[j] = acc; q[jj] = acc; nj = jj + 1;
  }
  float mx = -1e30f;
  for (int jj = 0; jj < nj; ++jj) mx = fmaxf(mx, q[jj]);
  red[t] = mx; __syncthreads();
  for (int sgap = 128; sgap; sgap >>= 1){
    if (t < sgap) red[t] = fmaxf(red[t], red[t + sgap]);
    __syncthreads();
  }
  mx = red[0]; __syncthreads();
  float se = 0.f;
  for (int jj = 0; jj < nj; ++jj) se += __expf(q[jj] - mx);
  red[t] = se; __syncthreads();
  for (int sgap = 128; sgap; sgap >>= 1){
    if (t < sgap) red[t] += red[t + sgap];
    __syncthreads();
  }
  if (t == 0){
    const float lp = qs[wid[r]] - mx - __logf(red[0]);
    atomicAdd(out + 1, -lp / (float)B);
  }
}

extern "C" void kernel_launch(void* const* d_in, const int* in_sizes, int n_in,
                              void* d_out, int out_size, void* d_ws, size_t ws_size,
                              hipStream_t stream)
{
  const float* msg    = (const float*)d_in[0];
  const float* f_src  = (const float*)d_in[1];
  const float* f_dst  = (const float*)d_in[2];
  const float* x_T    = (const float*)d_in[3];
  const float* x_G    = (const float*)d_in[4];
  const float* expand = (const float*)d_in[5];
  const float* wz = (const float*)d_in[6];
  const float* uz = (const float*)d_in[7];
  const float* bz = (const float*)d_in[8];
  const float* wr = (const float*)d_in[9];
  const float* ur = (const float*)d_in[10];
  const float* br = (const float*)d_in[11];
  const float* w  = (const float*)d_in[12];
  const float* u  = (const float*)d_in[13];
  const float* b  = (const float*)d_in[14];
  const float* w_d1 = (const float*)d_in[15];
  const float* w_d2 = (const float*)d_in[16];
  const float* b_d1 = (const float*)d_in[17];
  const float* a_dT = (const float*)d_in[18];
  const float* a_dG = (const float*)d_in[19];
  const float* w_d3 = (const float*)d_in[20];
  const float* w_d4 = (const float*)d_in[21];
  const float* b_d2 = (const float*)d_in[22];
  const float* u_d  = (const float*)d_in[23];
  const float* b_d3 = (const float*)d_in[24];
  const float* w_l1 = (const float*)d_in[25];
  const float* w_l2 = (const float*)d_in[26];
  const float* b_l1 = (const float*)d_in[27];
  const float* a_lT = (const float*)d_in[28];
  const float* a_lG = (const float*)d_in[29];
  const float* u_l  = (const float*)d_in[30];
  const float* b_l2 = (const float*)d_in[31];
  const int* lg_src = (const int*)d_in[32];
  const int* lg_dst = (const int*)d_in[33];
  const int* eids   = (const int*)d_in[34];
  const int* wid    = (const int*)d_in[35];

  const int d = 128;
  const int E   = in_sizes[0] / d;
  const int ELG = in_sizes[32];
  const int B   = in_sizes[34];
  const int V   = in_sizes[31];
  const int nT  = (in_sizes[3] / d) / B;
  const int nG  = (in_sizes[4] / d) / B;

  const size_t EB = (size_t)E * d * sizeof(float);
  const size_t BB = (size_t)B * d * sizeof(float);
  char* p = (char*)d_ws;
  float* buf0 = (float*)p; p += EB;   // R -> z
  float* buf1 = (float*)p; p += EB;   // s -> msg_new (in-place)
  float* buf2 = (float*)p; p += EB;   // srh -> sum_h
  float* fs_e = (float*)p; p += BB;
  float* sh_e = (float*)p; p += BB;
  float* m_e  = (float*)p; p += BB;
  float* h_t  = (float*)p; p += BB;
  float* haTd = (float*)p; p += BB;
  float* haGd = (float*)p; p += BB;
  float* haTl = (float*)p; p += BB;
  float* haGl = (float*)p; p += BB;
  float* c_d  = (float*)p; p += 2 * BB;
  float* c_l  = (float*)p; p += 2 * BB;
  float* z_d  = (float*)p; p += BB;
  float* z_l  = (float*)p; p += BB;
  // CSR scratch
  int* cnt     = (int*)p; p += (size_t)E * sizeof(int);
  int* offsets = (int*)p; p += (size_t)(E + 1) * sizeof(int);
  int* ticket  = (int*)p; p += (size_t)ELG * sizeof(int);
  int* csr_src = (int*)p; p += (size_t)ELG * sizeof(int);
  int* bsum    = (int*)p; p += (size_t)((E + SCAN_CHUNK - 1) / SCAN_CHUNK + 1) * sizeof(int);
  // bf16 transposed weights (shorts): offsets per wprep table, total 294912
  p = (char*)(((size_t)p + 255) & ~(size_t)255);
  short* wt = (short*)p; p += 294912 * sizeof(short);

  hipMemsetAsync(cnt, 0, (size_t)E * sizeof(int), stream);
  hipMemsetAsync(d_out, 0, 2 * sizeof(float), stream);

  const int nb = (E + SCAN_CHUNK - 1) / SCAN_CHUNK;
  const int GROW = (E * 32 + 255) / 256;
  const int GE = E / 64, GB = B / 64;

  // weights -> bf16 [col][k]
  wprep_kernel<<<dim3(24, 10), 256, 0, stream>>>(wr, ur, wz, uz, w, u, w_d1, w_d2,
                                                 a_dT, a_dG, a_lT, a_lG,
                                                 w_d3, w_d4, w_l1, w_l2, wt);

  // ---- CSR build (by lg_dst), reused for both segment sums ----
  csr_count_kernel<<<(ELG + 255) / 256, 256, 0, stream>>>(lg_dst, ELG, cnt, ticket);
  scan_totals_kernel<<<nb, 256, 0, stream>>>(cnt, E, bsum);
  scan_serial_kernel<<<1, 64, 0, stream>>>(bsum, nb, offsets, E);
  scan_write_kernel<<<nb, 256, 0, stream>>>(cnt, E, bsum, offsets);
  csr_fill_kernel<<<(ELG + 255) / 256, 256, 0, stream>>>(lg_src, lg_dst, ticket, ELG, offsets, csr_src);

  // R = sigmoid(f_dst@wr + msg@ur + br) * msg           -> buf0
  mfma_gemm_kernel<<<GE, 256, 0, stream>>>(E, f_dst, 128, msg, 128, wt + 0, 256,
                                           br, EPI_SIGMUL, msg, nullptr, buf0);
  // s = segsum(msg), srh = segsum(R)                    -> buf1, buf2
  gather2_csr_kernel<<<GROW, 256, 0, stream>>>(offsets, csr_src, E, msg, buf0, buf1, buf2);
  // z = sigmoid(f_src@wz + s@uz + bz)                   -> buf0
  mfma_gemm_kernel<<<GE, 256, 0, stream>>>(E, f_src, 128, buf1, 128, wt + 32768, 256,
                                           bz, EPI_SIGMOID, nullptr, nullptr, buf0);
  // msg_new = (1-z)*s + z*tanh(f_src@w + srh@u + b)     -> buf1 (in-place over s)
  mfma_gemm_kernel<<<GE, 256, 0, stream>>>(E, f_src, 128, buf2, 128, wt + 65536, 256,
                                           b, EPI_GRUMIX, buf0, buf1, buf1);
  // sum_h = segsum(msg_new)                             -> buf2
  gather1_csr_kernel<<<GROW, 256, 0, stream>>>(offsets, csr_src, E, buf1, buf2);
  // gathers at eids
  gather3_kernel<<<(B * 32 + 255) / 256, 256, 0, stream>>>(eids, B, f_src, buf2, buf1,
                                                           fs_e, sh_e, m_e);
  // h_t = relu(fs_e@w_d1 + sh_e@w_d2 + b_d1)
  mfma_gemm_kernel<<<GB, 256, 0, stream>>>(B, fs_e, 128, sh_e, 128, wt + 98304, 256,
                                           b_d1, EPI_RELU, nullptr, nullptr, h_t);
  // attention projections
  mfma_gemm_kernel<<<GB, 256, 0, stream>>>(B, h_t, 128, nullptr, 0, wt + 131072, 128,
                                           nullptr, EPI_NONE, nullptr, nullptr, haTd);
  mfma_gemm_kernel<<<GB, 256, 0, stream>>>(B, h_t, 128, nullptr, 0, wt + 147456, 128,
                                           nullptr, EPI_NONE, nullptr, nullptr, haGd);
  mfma_gemm_kernel<<<GB, 256, 0, stream>>>(B, m_e, 128, nullptr, 0, wt + 163840, 128,
                                           nullptr, EPI_NONE, nullptr, nullptr, haTl);
  mfma_gemm_kernel<<<GB, 256, 0, stream>>>(B, m_e, 128, nullptr, 0, wt + 180224, 128,
                                           nullptr, EPI_NONE, nullptr, nullptr, haGl);
  // fused attention (both heads share one pass over x)
  attn_kernel<<<B, 64, 0, stream>>>(x_T, nT, haTd, haTl, c_d, c_l, 2 * d, 0);
  attn_kernel<<<B, 64, 0, stream>>>(x_G, nG, haGd, haGl, c_d, c_l, 2 * d, d);
  // z_d = relu(h_t@w_d3 + c_d@w_d4 + b_d2)
  mfma_gemm_kernel<<<GB, 256, 0, stream>>>(B, h_t, 128, c_d, 256, wt + 196608, 384,
                                           b_d2, EPI_RELU, nullptr, nullptr, z_d);
  // z_l = relu(m_e@w_l1 + c_l@w_l2 + b_l1)
  mfma_gemm_kernel<<<GB, 256, 0, stream>>>(B, m_e, 128, c_l, 256, wt + 245760, 384,
                                           b_l1, EPI_RELU, nullptr, nullptr, z_l);
  // losses
  ce_topo_kernel<<<(B + 3) / 4, 256, 0, stream>>>(z_d, u_d, b_d3, expand, (float*)d_out, B);
  ce_label_kernel<<<B, 256, 0, stream>>>(z_l, u_l, b_l2, wid, (float*)d_out, B, V);
}